// Round 1
// baseline (359.646 us; speedup 1.0000x reference)
//
#include <hip/hip_runtime.h>
#include <math.h>

#define NN 10000
#define EE 160000
#define EPSBN 1e-5f

// ---------------- CSR build ----------------

__global__ void count_kernel(const int* __restrict__ dst, int* __restrict__ deg, int E) {
    int e = blockIdx.x * blockDim.x + threadIdx.x;
    if (e < E) atomicAdd(&deg[dst[e]], 1);
}

__global__ __launch_bounds__(1024) void scan_kernel(const int* __restrict__ deg, int* __restrict__ off,
                                                    int* __restrict__ cursor, int n) {
    __shared__ int sm[1024];
    const int C = 10;
    int t = threadIdx.x;
    int base = t * C;
    int loc[C];
    int acc = 0;
#pragma unroll
    for (int i = 0; i < C; i++) {
        int idx = base + i;
        int v = (idx < n) ? deg[idx] : 0;
        loc[i] = acc;
        acc += v;
    }
    sm[t] = acc;
    __syncthreads();
    for (int d = 1; d < 1024; d <<= 1) {
        int v = (t >= d) ? sm[t - d] : 0;
        __syncthreads();
        sm[t] += v;
        __syncthreads();
    }
    int prefix = (t > 0) ? sm[t - 1] : 0;
#pragma unroll
    for (int i = 0; i < C; i++) {
        int idx = base + i;
        if (idx < n) {
            int o = prefix + loc[i];
            off[idx] = o;
            cursor[idx] = o;
        }
    }
    if (t == 1023) off[n] = sm[1023];
}

__global__ void fill_kernel(const int* __restrict__ src, const int* __restrict__ dst,
                            const float* __restrict__ ew, int* __restrict__ cursor,
                            int* __restrict__ psrc, float* __restrict__ pew, int E) {
    int e = blockIdx.x * blockDim.x + threadIdx.x;
    if (e < E) {
        int d = dst[e];
        int slot = atomicAdd(&cursor[d], 1);
        psrc[slot] = src[e];
        pew[slot] = ew[e];
    }
}

// ---------------- fused GEMM: C[N, 2*fo] = A[M,K] @ [Brel | Broot] ----------------

__global__ __launch_bounds__(256) void gemm_kernel(const float* __restrict__ A,
                                                   const float* __restrict__ Brel,
                                                   const float* __restrict__ Broot,
                                                   float* __restrict__ C, int M, int K, int fo) {
    __shared__ float As[16][64];
    __shared__ float Bs[16][64];

    int m0 = blockIdx.x * 64;
    int n0 = blockIdx.y * 64;
    const float* B;
    int bcol;
    if (n0 < fo) { B = Brel; bcol = n0; } else { B = Broot; bcol = n0 - fo; }

    int t = threadIdx.x;
    int a_m = t >> 2;            // 0..63
    int a_k = (t & 3) * 4;       // 0,4,8,12
    int b_k = t >> 4;            // 0..15
    int b_n = (t & 15) * 4;      // 0..60
    int tx = t & 15, ty = t >> 4;

    float acc[4][4];
#pragma unroll
    for (int i = 0; i < 4; i++)
#pragma unroll
        for (int j = 0; j < 4; j++) acc[i][j] = 0.f;

    int Nout = 2 * fo;

    for (int k0 = 0; k0 < K; k0 += 16) {
        // load A tile 64x16 (scalar loads: K may be odd, e.g. 517)
        {
            int gm = m0 + a_m;
            float v0 = 0.f, v1 = 0.f, v2 = 0.f, v3 = 0.f;
            if (gm < M) {
                const float* ap = A + (size_t)gm * K;
                int gk = k0 + a_k;
                if (gk + 0 < K) v0 = ap[gk + 0];
                if (gk + 1 < K) v1 = ap[gk + 1];
                if (gk + 2 < K) v2 = ap[gk + 2];
                if (gk + 3 < K) v3 = ap[gk + 3];
            }
            As[a_k + 0][a_m] = v0;
            As[a_k + 1][a_m] = v1;
            As[a_k + 2][a_m] = v2;
            As[a_k + 3][a_m] = v3;
        }
        // load B tile 16x64 (row stride fo is multiple of 16B)
        {
            int gk = k0 + b_k;
            float4 v = make_float4(0.f, 0.f, 0.f, 0.f);
            if (gk < K) v = *(const float4*)(B + (size_t)gk * fo + bcol + b_n);
            Bs[b_k][b_n + 0] = v.x;
            Bs[b_k][b_n + 1] = v.y;
            Bs[b_k][b_n + 2] = v.z;
            Bs[b_k][b_n + 3] = v.w;
        }
        __syncthreads();
#pragma unroll
        for (int kk = 0; kk < 16; kk++) {
            float4 a = *(const float4*)&As[kk][ty * 4];
            float4 b = *(const float4*)&Bs[kk][tx * 4];
            acc[0][0] += a.x * b.x; acc[0][1] += a.x * b.y; acc[0][2] += a.x * b.z; acc[0][3] += a.x * b.w;
            acc[1][0] += a.y * b.x; acc[1][1] += a.y * b.y; acc[1][2] += a.y * b.z; acc[1][3] += a.y * b.w;
            acc[2][0] += a.z * b.x; acc[2][1] += a.z * b.y; acc[2][2] += a.z * b.z; acc[2][3] += a.z * b.w;
            acc[3][0] += a.w * b.x; acc[3][1] += a.w * b.y; acc[3][2] += a.w * b.z; acc[3][3] += a.w * b.w;
        }
        __syncthreads();
    }

#pragma unroll
    for (int i = 0; i < 4; i++) {
        int gm = m0 + ty * 4 + i;
        if (gm < M) {
            float4 v = make_float4(acc[i][0], acc[i][1], acc[i][2], acc[i][3]);
            *(float4*)(C + (size_t)gm * Nout + n0 + tx * 4) = v;
        }
    }
}

// ---------------- aggregation: h_pre[n,f] = b_rel[f] + y_root[n,f] + sum_e ew*y_rel[src,f] ----------------

__global__ void agg_kernel(const float* __restrict__ gout, const int* __restrict__ off,
                           const int* __restrict__ psrc, const float* __restrict__ pew,
                           const float* __restrict__ brel, float* __restrict__ hpre, int fo) {
    int n = blockIdx.x;
    int f = threadIdx.x;
    int Nout = 2 * fo;
    float acc = gout[(size_t)n * Nout + fo + f] + brel[f];
    int e0 = off[n], e1 = off[n + 1];
    for (int e = e0; e < e1; e++) {
        int s = psrc[e];
        float w = pew[e];
        acc += w * gout[(size_t)s * Nout + f];
    }
    hpre[(size_t)n * fo + f] = acc;
}

// ---------------- BN stats ----------------

__global__ void stats_kernel(const float* __restrict__ hpre, float* __restrict__ sum,
                             float* __restrict__ sumsq, int Nn, int fo, int rpb) {
    int f = threadIdx.x;
    int r0 = blockIdx.x * rpb;
    int r1 = r0 + rpb;
    if (r1 > Nn) r1 = Nn;
    float s = 0.f, s2 = 0.f;
    for (int r = r0; r < r1; r++) {
        float v = hpre[(size_t)r * fo + f];
        s += v;
        s2 += v * v;
    }
    atomicAdd(&sum[f], s);
    atomicAdd(&sumsq[f], s2);
}

__global__ void bnparams_kernel(const float* __restrict__ sum, const float* __restrict__ sumsq,
                                const float* __restrict__ g, const float* __restrict__ b,
                                float* __restrict__ scalev, float* __restrict__ shiftv, int Nn, int fo) {
    int f = threadIdx.x;
    if (f < fo) {
        float mean = sum[f] / (float)Nn;
        float var = sumsq[f] / (float)Nn - mean * mean;
        if (var < 0.f) var = 0.f;
        float sc = g[f] * rsqrtf(var + EPSBN);
        scalev[f] = sc;
        shiftv[f] = b[f] - mean * sc;
    }
}

__global__ void norm_relu_kernel(const float* __restrict__ hpre, const float* __restrict__ sc,
                                 const float* __restrict__ sh, float* __restrict__ hout,
                                 int total4, int fo) {
    int i = blockIdx.x * blockDim.x + threadIdx.x;
    if (i >= total4) return;
    int base = i * 4;
    float4 v = *(const float4*)(hpre + base);
    int f0 = base % fo;
    float4 s = *(const float4*)(sc + f0);
    float4 t = *(const float4*)(sh + f0);
    v.x = fmaxf(0.f, v.x * s.x + t.x);
    v.y = fmaxf(0.f, v.y * s.y + t.y);
    v.z = fmaxf(0.f, v.z * s.z + t.z);
    v.w = fmaxf(0.f, v.w * s.w + t.w);
    *(float4*)(hout + base) = v;
}

// ---------------- head: dot(h[n,:64], w_lin) + b -> log_sigmoid ----------------

__global__ void head_kernel(const float* __restrict__ h, const float* __restrict__ wlin,
                            const float* __restrict__ blin, float* __restrict__ tmp, int Nn) {
    int lane = threadIdx.x & 63;
    int wv = threadIdx.x >> 6;
    int n = blockIdx.x * 4 + wv;
    if (n >= Nn) return;
    float p = h[(size_t)n * 64 + lane] * wlin[lane];
#pragma unroll
    for (int o = 32; o > 0; o >>= 1) p += __shfl_down(p, o, 64);
    if (lane == 0) {
        float x = p + blin[0];
        float ls = (x >= 0.f) ? (-log1pf(expf(-x))) : (x - log1pf(expf(x)));
        tmp[n] = ls;
    }
}

__global__ __launch_bounds__(1024) void lse_kernel(const float* __restrict__ tmp, float* __restrict__ lse, int Nn) {
    __shared__ float sm[1024];
    int t = threadIdx.x;
    float m = -INFINITY;
    for (int i = t; i < Nn; i += 1024) m = fmaxf(m, tmp[i]);
    sm[t] = m;
    __syncthreads();
    for (int s = 512; s > 0; s >>= 1) {
        if (t < s) sm[t] = fmaxf(sm[t], sm[t + s]);
        __syncthreads();
    }
    float M = sm[0];
    __syncthreads();
    float acc = 0.f;
    for (int i = t; i < Nn; i += 1024) acc += expf(tmp[i] - M);
    sm[t] = acc;
    __syncthreads();
    for (int s = 512; s > 0; s >>= 1) {
        if (t < s) sm[t] += sm[t + s];
        __syncthreads();
    }
    if (t == 0) lse[0] = M + logf(sm[0]);
}

__global__ void final_kernel(const float* __restrict__ tmp, const float* __restrict__ lse,
                             float* __restrict__ out, int Nn) {
    int i = blockIdx.x * blockDim.x + threadIdx.x;
    if (i < Nn) out[i] = tmp[i] - lse[0];
}

// ---------------- launch ----------------

extern "C" void kernel_launch(void* const* d_in, const int* in_sizes, int n_in,
                              void* d_out, int out_size, void* d_ws, size_t ws_size,
                              hipStream_t stream) {
    const float* x    = (const float*)d_in[0];
    const int*   ei   = (const int*)d_in[1];
    const float* ew   = (const float*)d_in[2];
    const int* src = ei;
    const int* dst = ei + EE;

    const float* wrel[3]  = { (const float*)d_in[3],  (const float*)d_in[8],  (const float*)d_in[13] };
    const float* brel[3]  = { (const float*)d_in[4],  (const float*)d_in[9],  (const float*)d_in[14] };
    const float* wroot[3] = { (const float*)d_in[5],  (const float*)d_in[10], (const float*)d_in[15] };
    const float* bng[3]   = { (const float*)d_in[6],  (const float*)d_in[11], (const float*)d_in[16] };
    const float* bnb[3]   = { (const float*)d_in[7],  (const float*)d_in[12], (const float*)d_in[17] };
    const float* wlin = (const float*)d_in[18];
    const float* blin = (const float*)d_in[19];
    float* out = (float*)d_out;

    const int Kdims[3]  = { 517, 256, 128 };
    const int fodims[3] = { 256, 128, 64 };

    // workspace layout (floats)
    float* gemm_out = (float*)d_ws;                 // NN*512
    float* h_pre    = gemm_out + (size_t)NN * 512;  // NN*256
    float* h_buf    = h_pre + (size_t)NN * 256;     // NN*256
    int*   deg      = (int*)(h_buf + (size_t)NN * 256); // NN
    int*   off      = deg + NN;                     // NN+1
    int*   cursor   = off + NN + 1;                 // NN
    int*   psrc     = cursor + NN;                  // EE
    float* pew      = (float*)(psrc + EE);          // EE
    float* ssum     = pew + EE;                     // 256
    float* ssumsq   = ssum + 256;                   // 256
    float* scalev   = ssumsq + 256;                 // 256
    float* shiftv   = scalev + 256;                 // 256
    float* tmp      = shiftv + 256;                 // NN
    float* lse      = tmp + NN;                     // 1

    // ---- CSR build (shared by all 3 layers) ----
    hipMemsetAsync(deg, 0, NN * sizeof(int), stream);
    count_kernel<<<(EE + 255) / 256, 256, 0, stream>>>(dst, deg, EE);
    scan_kernel<<<1, 1024, 0, stream>>>(deg, off, cursor, NN);
    fill_kernel<<<(EE + 255) / 256, 256, 0, stream>>>(src, dst, ew, cursor, psrc, pew, EE);

    const float* hin = x;
    for (int l = 0; l < 3; l++) {
        int K = Kdims[l], fo = fodims[l];
        dim3 ggrid((NN + 63) / 64, (2 * fo) / 64);
        gemm_kernel<<<ggrid, 256, 0, stream>>>(hin, wrel[l], wroot[l], gemm_out, NN, K, fo);
        agg_kernel<<<NN, fo, 0, stream>>>(gemm_out, off, psrc, pew, brel[l], h_pre, fo);
        hipMemsetAsync(ssum, 0, 512 * sizeof(float), stream);
        stats_kernel<<<(NN + 49) / 50, fo, 0, stream>>>(h_pre, ssum, ssumsq, NN, fo, 50);
        bnparams_kernel<<<1, fo, 0, stream>>>(ssum, ssumsq, bng[l], bnb[l], scalev, shiftv, NN, fo);
        int total4 = NN * fo / 4;
        norm_relu_kernel<<<(total4 + 255) / 256, 256, 0, stream>>>(h_pre, scalev, shiftv, h_buf, total4, fo);
        hin = h_buf;
    }

    head_kernel<<<(NN + 3) / 4, 256, 0, stream>>>(h_buf, wlin, blin, tmp, NN);
    lse_kernel<<<1, 1024, 0, stream>>>(tmp, lse, NN);
    final_kernel<<<(NN + 255) / 256, 256, 0, stream>>>(tmp, lse, out, NN);
}

// Round 2
// 253.308 us; speedup vs baseline: 1.4198x; 1.4198x over previous
//
#include <hip/hip_runtime.h>
#include <math.h>

#define NN 10000
#define EE 160000
#define MP 10112   // 79*128, padded node count
#define EPSBN 1e-5f

typedef __attribute__((ext_vector_type(8))) short short8;
typedef __attribute__((ext_vector_type(4))) float f32x4;

__device__ __forceinline__ short f2bf(float f) {
    union { float f; unsigned u; } v; v.f = f;
    unsigned r = v.u + 0x7FFF + ((v.u >> 16) & 1);
    return (short)(r >> 16);
}
__device__ __forceinline__ float bf2f(unsigned short u) {
    union { unsigned u; float f; } v; v.u = ((unsigned)u) << 16;
    return v.f;
}
__device__ __forceinline__ void gload16(const short* g, short* l) {
    __builtin_amdgcn_global_load_lds((const __attribute__((address_space(1))) void*)g,
                                     (__attribute__((address_space(3))) void*)l, 16, 0, 0);
}

// ---------------- CSR build ----------------

__global__ void count_kernel(const int* __restrict__ dst, int* __restrict__ deg, int E) {
    int e = blockIdx.x * blockDim.x + threadIdx.x;
    if (e < E) atomicAdd(&deg[dst[e]], 1);
}

__global__ __launch_bounds__(1024) void scan_kernel(const int* __restrict__ deg, int* __restrict__ off,
                                                    int* __restrict__ cursor, int n) {
    __shared__ int sm[1024];
    const int C = 10;
    int t = threadIdx.x;
    int base = t * C;
    int loc[C];
    int acc = 0;
#pragma unroll
    for (int i = 0; i < C; i++) {
        int idx = base + i;
        int v = (idx < n) ? deg[idx] : 0;
        loc[i] = acc;
        acc += v;
    }
    sm[t] = acc;
    __syncthreads();
    for (int d = 1; d < 1024; d <<= 1) {
        int v = (t >= d) ? sm[t - d] : 0;
        __syncthreads();
        sm[t] += v;
        __syncthreads();
    }
    int prefix = (t > 0) ? sm[t - 1] : 0;
#pragma unroll
    for (int i = 0; i < C; i++) {
        int idx = base + i;
        if (idx < n) {
            int o = prefix + loc[i];
            off[idx] = o;
            cursor[idx] = o;
        }
    }
    if (t == 1023) off[n] = sm[1023];
}

__global__ void fill_kernel(const int* __restrict__ src, const int* __restrict__ dst,
                            const float* __restrict__ ew, int* __restrict__ cursor,
                            int* __restrict__ psrc, float* __restrict__ pew, int E) {
    int e = blockIdx.x * blockDim.x + threadIdx.x;
    if (e < E) {
        int d = dst[e];
        int slot = atomicAdd(&cursor[d], 1);
        psrc[slot] = src[e];
        pew[slot] = ew[e];
    }
}

// ---------------- converts ----------------

__global__ void conv_x_kernel(const float* __restrict__ x, short* __restrict__ A) {
    const int Kp = 576, K = 517;
    int m = blockIdx.x;
    for (int k = threadIdx.x; k < Kp; k += 256) {
        short v = 0;
        if (m < NN && k < K) v = f2bf(x[(size_t)m * K + k]);
        A[(size_t)m * Kp + k] = v;
    }
}

// Bt[j][k], j in [0,2fo): j<fo -> wrel[k][j], else wroot[k][j-fo]; zero-pad k>=K
__global__ void conv_w_kernel(const float* __restrict__ wrel, const float* __restrict__ wroot,
                              short* __restrict__ Bt, int K, int Kp, int fo) {
    int j = blockIdx.x;
    const float* W = (j < fo) ? wrel : wroot;
    int col = (j < fo) ? j : j - fo;
    for (int k = threadIdx.x; k < Kp; k += 256) {
        short v = 0;
        if (k < K) v = f2bf(W[(size_t)k * fo + col]);
        Bt[(size_t)j * Kp + k] = v;
    }
}

// ---------------- MFMA GEMM: [MP,Kp]bf16 @ Bt[2fo,Kp]^T -> Yrel bf16 [MP,fo] + Yroot f32 [MP,fo] ----------------
// 128x64 tile, BK=64, 4 waves each 32 rows x 64 cols (2x4 frags of 16x16x32)

__global__ __launch_bounds__(256) void mfma_gemm(const short* __restrict__ A,
                                                 const short* __restrict__ Bt,
                                                 short* __restrict__ Yrel,
                                                 float* __restrict__ Yroot,
                                                 int Kp, int fo) {
    __shared__ short Als[128 * 64];
    __shared__ short Bls[64 * 64];
    int m0 = blockIdx.x * 128;
    int n0 = blockIdx.y * 64;
    int t = threadIdx.x;
    int lane = t & 63;
    int wid = t >> 6;

    f32x4 acc[2][4];
#pragma unroll
    for (int i = 0; i < 2; i++)
#pragma unroll
        for (int j = 0; j < 4; j++) acc[i][j] = (f32x4){0.f, 0.f, 0.f, 0.f};

    for (int k0 = 0; k0 < Kp; k0 += 64) {
        // A tile: 128x64 shorts = 1024 x 16B chunks, 4/thread. XOR-swizzled source.
#pragma unroll
        for (int i = 0; i < 4; i++) {
            int idx = i * 256 + t;
            int row = idx >> 3;
            int pc = idx & 7;
            int lc = pc ^ (row & 7);
            gload16(A + (size_t)(m0 + row) * Kp + k0 + lc * 8, &Als[idx * 8]);
        }
        // B tile: 64x64 shorts = 512 chunks, 2/thread.
#pragma unroll
        for (int i = 0; i < 2; i++) {
            int idx = i * 256 + t;
            int row = idx >> 3;
            int pc = idx & 7;
            int lc = pc ^ (row & 7);
            gload16(Bt + (size_t)(n0 + row) * Kp + k0 + lc * 8, &Bls[idx * 8]);
        }
        __syncthreads();
#pragma unroll
        for (int kk = 0; kk < 2; kk++) {
            short8 af[2], bfr[4];
#pragma unroll
            for (int mi = 0; mi < 2; mi++) {
                int row = wid * 32 + mi * 16 + (lane & 15);
                int cc = kk * 4 + (lane >> 4);
                af[mi] = *(const short8*)&Als[(row * 8 + (cc ^ (row & 7))) * 8];
            }
#pragma unroll
            for (int ni = 0; ni < 4; ni++) {
                int row = ni * 16 + (lane & 15);
                int cc = kk * 4 + (lane >> 4);
                bfr[ni] = *(const short8*)&Bls[(row * 8 + (cc ^ (row & 7))) * 8];
            }
#pragma unroll
            for (int mi = 0; mi < 2; mi++)
#pragma unroll
                for (int ni = 0; ni < 4; ni++)
                    acc[mi][ni] = __builtin_amdgcn_mfma_f32_16x16x32_bf16(af[mi], bfr[ni], acc[mi][ni], 0, 0, 0);
        }
        __syncthreads();
    }

#pragma unroll
    for (int mi = 0; mi < 2; mi++) {
#pragma unroll
        for (int ni = 0; ni < 4; ni++) {
            int gn = n0 + ni * 16 + (lane & 15);
            int row0 = m0 + wid * 32 + mi * 16 + (lane >> 4) * 4;
            f32x4 v = acc[mi][ni];
#pragma unroll
            for (int r = 0; r < 4; r++) {
                int gm = row0 + r;
                if (gn < fo) Yrel[(size_t)gm * fo + gn] = f2bf(v[r]);
                else         Yroot[(size_t)gm * fo + (gn - fo)] = v[r];
            }
        }
    }
}

// ---------------- aggregation: hio[n,f] += brel[f] + sum_e w*Yrel[src,f] (hio holds Yroot) ----------------

template <int FO>
__global__ __launch_bounds__(256) void agg_kernel(const short* __restrict__ Yrel,
                                                  float* __restrict__ hio,
                                                  const int* __restrict__ off,
                                                  const int* __restrict__ psrc,
                                                  const float* __restrict__ pew,
                                                  const float* __restrict__ brel) {
    const int G = FO / 2;
    const int NPB = 256 / G;
    int g = threadIdx.x / G;
    int tf = threadIdx.x % G;
    int n = blockIdx.x * NPB + g;
    int f = tf * 2;
    float a0 = 0.f, a1 = 0.f;
    int e0 = off[n], e1 = off[n + 1];
    for (int e = e0; e < e1; e++) {
        int s = psrc[e];
        float w = pew[e];
        unsigned pk = *(const unsigned*)(Yrel + (size_t)s * FO + f);
        a0 += w * bf2f((unsigned short)(pk & 0xffff));
        a1 += w * bf2f((unsigned short)(pk >> 16));
    }
    size_t o = (size_t)n * FO + f;
    hio[o]     += a0 + brel[f];
    hio[o + 1] += a1 + brel[f + 1];
}

// ---------------- BN ----------------

__global__ void stats_kernel(const float* __restrict__ hpre, float* __restrict__ sum,
                             float* __restrict__ sumsq, int fo, int rpb) {
    int f = threadIdx.x;
    int r0 = blockIdx.x * rpb;
    int r1 = r0 + rpb;
    if (r1 > NN) r1 = NN;
    float s = 0.f, s2 = 0.f;
    for (int r = r0; r < r1; r++) {
        float v = hpre[(size_t)r * fo + f];
        s += v;
        s2 += v * v;
    }
    atomicAdd(&sum[f], s);
    atomicAdd(&sumsq[f], s2);
}

__global__ void bnparams_kernel(const float* __restrict__ sum, const float* __restrict__ sumsq,
                                const float* __restrict__ g, const float* __restrict__ b,
                                float* __restrict__ scalev, float* __restrict__ shiftv, int fo) {
    int f = threadIdx.x;
    if (f < fo) {
        float mean = sum[f] / (float)NN;
        float var = sumsq[f] / (float)NN - mean * mean;
        if (var < 0.f) var = 0.f;
        float sc = g[f] * rsqrtf(var + EPSBN);
        scalev[f] = sc;
        shiftv[f] = b[f] - mean * sc;
    }
}

// norm+relu+convert-to-bf16, zero-padding rows >= NN
__global__ void norm_relu_bf16(const float* __restrict__ hpre, const float* __restrict__ sc,
                               const float* __restrict__ sh, short* __restrict__ Hout, int fo) {
    int m = blockIdx.x;
    if (m < NN) {
        for (int f = threadIdx.x; f < fo; f += 256) {
            float v = fmaxf(0.f, hpre[(size_t)m * fo + f] * sc[f] + sh[f]);
            Hout[(size_t)m * fo + f] = f2bf(v);
        }
    } else {
        for (int f = threadIdx.x; f < fo; f += 256) Hout[(size_t)m * fo + f] = 0;
    }
}

// ---------------- head ----------------

__global__ void head_kernel(const short* __restrict__ h, const float* __restrict__ wlin,
                            const float* __restrict__ blin, float* __restrict__ tmp) {
    int lane = threadIdx.x & 63;
    int wv = threadIdx.x >> 6;
    int n = blockIdx.x * 4 + wv;
    if (n >= NN) return;
    float p = bf2f((unsigned short)h[(size_t)n * 64 + lane]) * wlin[lane];
#pragma unroll
    for (int o = 32; o > 0; o >>= 1) p += __shfl_down(p, o, 64);
    if (lane == 0) {
        float x = p + blin[0];
        float ls = (x >= 0.f) ? (-log1pf(expf(-x))) : (x - log1pf(expf(x)));
        tmp[n] = ls;
    }
}

__global__ __launch_bounds__(1024) void lse_kernel(const float* __restrict__ tmp, float* __restrict__ lse) {
    __shared__ float sm[1024];
    int t = threadIdx.x;
    float m = -INFINITY;
    for (int i = t; i < NN; i += 1024) m = fmaxf(m, tmp[i]);
    sm[t] = m;
    __syncthreads();
    for (int s = 512; s > 0; s >>= 1) {
        if (t < s) sm[t] = fmaxf(sm[t], sm[t + s]);
        __syncthreads();
    }
    float M = sm[0];
    __syncthreads();
    float acc = 0.f;
    for (int i = t; i < NN; i += 1024) acc += expf(tmp[i] - M);
    sm[t] = acc;
    __syncthreads();
    for (int s = 512; s > 0; s >>= 1) {
        if (t < s) sm[t] += sm[t + s];
        __syncthreads();
    }
    if (t == 0) lse[0] = M + logf(sm[0]);
}

__global__ void final_kernel(const float* __restrict__ tmp, const float* __restrict__ lse,
                             float* __restrict__ out) {
    int i = blockIdx.x * blockDim.x + threadIdx.x;
    if (i < NN) out[i] = tmp[i] - lse[0];
}

// ---------------- launch ----------------

extern "C" void kernel_launch(void* const* d_in, const int* in_sizes, int n_in,
                              void* d_out, int out_size, void* d_ws, size_t ws_size,
                              hipStream_t stream) {
    const float* x  = (const float*)d_in[0];
    const int* ei   = (const int*)d_in[1];
    const float* ew = (const float*)d_in[2];
    const int* src = ei;
    const int* dst = ei + EE;

    const float* wrel[3]  = { (const float*)d_in[3],  (const float*)d_in[8],  (const float*)d_in[13] };
    const float* brel[3]  = { (const float*)d_in[4],  (const float*)d_in[9],  (const float*)d_in[14] };
    const float* wroot[3] = { (const float*)d_in[5],  (const float*)d_in[10], (const float*)d_in[15] };
    const float* bng[3]   = { (const float*)d_in[6],  (const float*)d_in[11], (const float*)d_in[16] };
    const float* bnb[3]   = { (const float*)d_in[7],  (const float*)d_in[12], (const float*)d_in[17] };
    const float* wlin = (const float*)d_in[18];
    const float* blin = (const float*)d_in[19];
    float* out = (float*)d_out;

    const int Kdim[3] = { 517, 256, 128 };
    const int Kp[3]   = { 576, 256, 128 };
    const int fo[3]   = { 256, 128, 64 };

    char* p = (char*)d_ws;
    auto alloc = [&](size_t bytes) { char* r = p; p += (bytes + 255) & ~(size_t)255; return r; };

    short* A1  = (short*)alloc((size_t)MP * 576 * 2);
    short* H2  = (short*)alloc((size_t)MP * 256 * 2);
    short* H3  = (short*)alloc((size_t)MP * 128 * 2);
    short* H4  = (short*)alloc((size_t)MP * 64 * 2);
    short* B1t = (short*)alloc((size_t)512 * 576 * 2);
    short* B2t = (short*)alloc((size_t)256 * 256 * 2);
    short* B3t = (short*)alloc((size_t)128 * 128 * 2);
    short* Yrel = (short*)alloc((size_t)MP * 256 * 2);
    float* hio  = (float*)alloc((size_t)MP * 256 * 4);
    int* deg    = (int*)alloc(NN * 4);
    int* off    = (int*)alloc((NN + 4) * 4);
    int* cursor = (int*)alloc(NN * 4);
    int* psrc   = (int*)alloc(EE * 4);
    float* pew  = (float*)alloc(EE * 4);
    float* ssum = (float*)alloc(512 * 4);   // ssum[256] + ssumsq[256]
    float* ssumsq = ssum + 256;
    float* scalev = (float*)alloc(256 * 4);
    float* shiftv = (float*)alloc(256 * 4);
    float* tmp    = (float*)alloc(NN * 4);
    float* lse    = (float*)alloc(16);

    short* Ain[3]  = { A1, H2, H3 };
    short* Hout[3] = { H2, H3, H4 };
    short* Bt[3]   = { B1t, B2t, B3t };

    // CSR build (reused by all layers)
    hipMemsetAsync(deg, 0, NN * sizeof(int), stream);
    count_kernel<<<(EE + 255) / 256, 256, 0, stream>>>(dst, deg, EE);
    scan_kernel<<<1, 1024, 0, stream>>>(deg, off, cursor, NN);
    fill_kernel<<<(EE + 255) / 256, 256, 0, stream>>>(src, dst, ew, cursor, psrc, pew, EE);

    // converts
    conv_x_kernel<<<MP, 256, 0, stream>>>(x, A1);
    for (int l = 0; l < 3; l++)
        conv_w_kernel<<<2 * fo[l], 256, 0, stream>>>(wrel[l], wroot[l], Bt[l], Kdim[l], Kp[l], fo[l]);

    for (int l = 0; l < 3; l++) {
        dim3 ggrid(MP / 128, 2 * fo[l] / 64);
        mfma_gemm<<<ggrid, 256, 0, stream>>>(Ain[l], Bt[l], Yrel, hio, Kp[l], fo[l]);
        if (l == 0)      agg_kernel<256><<<5000, 256, 0, stream>>>(Yrel, hio, off, psrc, pew, brel[l]);
        else if (l == 1) agg_kernel<128><<<2500, 256, 0, stream>>>(Yrel, hio, off, psrc, pew, brel[l]);
        else             agg_kernel<64><<<1250, 256, 0, stream>>>(Yrel, hio, off, psrc, pew, brel[l]);
        hipMemsetAsync(ssum, 0, 512 * sizeof(float), stream);
        stats_kernel<<<250, fo[l], 0, stream>>>(hio, ssum, ssumsq, fo[l], 40);
        bnparams_kernel<<<1, fo[l], 0, stream>>>(ssum, ssumsq, bng[l], bnb[l], scalev, shiftv, fo[l]);
        norm_relu_bf16<<<MP, 256, 0, stream>>>(hio, scalev, shiftv, Hout[l], fo[l]);
    }

    head_kernel<<<(NN + 3) / 4, 256, 0, stream>>>(H4, wlin, blin, tmp);
    lse_kernel<<<1, 1024, 0, stream>>>(tmp, lse);
    final_kernel<<<(NN + 255) / 256, 256, 0, stream>>>(tmp, lse, out);
}